// Round 6
// baseline (938.531 us; speedup 1.0000x reference)
//
#include <hip/hip_runtime.h>

// ---------------- constants ----------------
#define BATCH 8
#define HH 64
#define WW 64
#define LSEQ 4096                    // HH*WW
#define BL 32768                     // BATCH*LSEQ
#define DM 768
#define CD 896                       // CONV_DIM
#define NPROJ 1676                   // D_IN_PROJ
#define NPAD 1792                    // padded to 14*128
#define NH 12
#define HD 64
#define DS 64
#define OUT_ELEMS 25165824           // BL*DM
#define KV_ELEMS 393216              // BATCH*NH*DS*HD
#define KVCHUNK 16                   // K-split for kv einsum

// workspace layout (bytes)
#define OFF_ZX   ((size_t)0)
#define SZ_ZX    ((size_t)BL * NPAD * 4)
#define OFF_XC   (OFF_ZX + SZ_ZX)
#define SZ_XC    ((size_t)BL * CD * 4)
#define OFF_DA   (OFF_XC + SZ_XC)
#define SZ_DA    ((size_t)BL * NH * 4)
#define OFF_UBF  (OFF_DA + SZ_DA)            // u bf16; later overlaid: Cb192 / KVt192 / yz bf16
#define SZ_UBF   ((size_t)BL * DM * 2)
#define OFF_WI   (OFF_UBF + SZ_UBF)
#define SZ_WI    ((size_t)NPAD * DM * 2)
#define OFF_WO   (OFF_WI + SZ_WI)
#define SZ_WO    ((size_t)DM * DM * 2)
#define OFF_CWT  (OFF_WO + SZ_WO)            // 9*896 floats

// overlays inside the UBF region (all consumers finish before yz is written)
#define OFF_CB   OFF_UBF                         // 32768*192*2 = 12.6 MB
#define OFF_KVT  (OFF_UBF + (size_t)20*1024*1024) // 8*768*192*2 = 2.36 MB

typedef __attribute__((ext_vector_type(4))) float f32x4;
typedef __attribute__((ext_vector_type(8))) short bf16x8;

__device__ __forceinline__ unsigned short f2bf(float f) {
    unsigned int u = __float_as_uint(f);
    u += 0x7FFFu + ((u >> 16) & 1u);   // round to nearest even
    return (unsigned short)(u >> 16);
}
__device__ __forceinline__ float bf2f(unsigned short h) {
    return __uint_as_float(((unsigned int)h) << 16);
}

__device__ __forceinline__ void gl2lds16(const void* g, void* l) {
    __builtin_amdgcn_global_load_lds(
        (const __attribute__((address_space(1))) unsigned int*)g,
        (__attribute__((address_space(3))) unsigned int*)l, 16, 0, 0);
}

// ---------------- conversion kernels ----------------
__global__ void cvt_u_kernel(const float* __restrict__ in, unsigned short* __restrict__ out, int n8) {
    int i = blockIdx.x * 256 + threadIdx.x;
    if (i >= n8) return;
    const float4* p = (const float4*)in + (size_t)i * 2;
    float4 a = p[0], b = p[1];
    union { unsigned short s[8]; uint4 v; } r;
    r.s[0] = f2bf(a.x); r.s[1] = f2bf(a.y); r.s[2] = f2bf(a.z); r.s[3] = f2bf(a.w);
    r.s[4] = f2bf(b.x); r.s[5] = f2bf(b.y); r.s[6] = f2bf(b.z); r.s[7] = f2bf(b.w);
    ((uint4*)out)[i] = r.v;
}

// w_in (1676,768) -> bf16 (1792,768) zero padded rows
__global__ void cvt_win_kernel(const float* __restrict__ in, unsigned short* __restrict__ out) {
    int i = blockIdx.x * 256 + threadIdx.x;        // i indexes groups of 8
    if (i >= NPAD * DM / 8) return;
    int row = (i * 8) / DM;
    union { unsigned short s[8]; uint4 v; } r;
    if (row < NPROJ) {
        const float4* p = (const float4*)in + (size_t)i * 2;
        float4 a = p[0], b = p[1];
        r.s[0] = f2bf(a.x); r.s[1] = f2bf(a.y); r.s[2] = f2bf(a.z); r.s[3] = f2bf(a.w);
        r.s[4] = f2bf(b.x); r.s[5] = f2bf(b.y); r.s[6] = f2bf(b.z); r.s[7] = f2bf(b.w);
    } else {
        r.v = make_uint4(0, 0, 0, 0);
    }
    ((uint4*)out)[i] = r.v;
}

// conv_w (896,1,3,3) -> cwT (9, 896)
__global__ void cvt_cw_kernel(const float* __restrict__ in, float* __restrict__ out) {
    int i = blockIdx.x * 256 + threadIdx.x;
    if (i >= 9 * CD) return;
    int tap = i / CD, c = i % CD;
    out[i] = in[c * 9 + tap];
}

// Cmat (xc[...,832:896]) -> split-precision K=192 layout [hi | lo | hi]
__global__ void cvt_c_kernel(const float* __restrict__ xc, unsigned short* __restrict__ Cb) {
    int i = blockIdx.x * 256 + threadIdx.x;     // BL*16 float4-groups
    if (i >= BL * 16) return;
    int row = i >> 4, c = (i & 15) * 4;
    float4 v = *(const float4*)&xc[(size_t)row * CD + (DM + DS) + c];
    ushort4 hi, lo;
    hi.x = f2bf(v.x); lo.x = f2bf(v.x - bf2f(hi.x));
    hi.y = f2bf(v.y); lo.y = f2bf(v.y - bf2f(hi.y));
    hi.z = f2bf(v.z); lo.z = f2bf(v.z - bf2f(hi.z));
    hi.w = f2bf(v.w); lo.w = f2bf(v.w - bf2f(hi.w));
    unsigned short* base = Cb + (size_t)row * 192;
    *(ushort4*)&base[c]       = hi;
    *(ushort4*)&base[64 + c]  = lo;
    *(ushort4*)&base[128 + c] = hi;
}

// KV (b,h,s,p) fp32 -> KVt (b, n=h*64+p, k=192) bf16 [H | H | L]
__global__ void cvt_kv_kernel(const float* __restrict__ KV, unsigned short* __restrict__ KVt) {
    int i = blockIdx.x * 256 + threadIdx.x;     // 8*768*64
    if (i >= BATCH * DM * DS) return;
    int s = i & 63;
    int n = (i >> 6) % DM;
    int b = i / (DM * DS);
    int h = n >> 6, p = n & 63;
    float x = KV[(((size_t)(b * NH + h) * DS + s) * HD) + p];
    unsigned short H = f2bf(x);
    unsigned short L = f2bf(x - bf2f(H));
    unsigned short* base = KVt + ((size_t)(b * DM + n)) * 192;
    base[s] = H; base[64 + s] = H; base[128 + s] = L;
}

// ---------------- bf16 GEMM (m97 structure): C(M,N) = A(M,K) * B(N,K)^T ----------------
__global__ __launch_bounds__(256) void gemm_bt_bf16(
    const unsigned short* __restrict__ A,
    const unsigned short* __restrict__ Bm,
    float* __restrict__ C, int M, int N, int K) {
    __shared__ unsigned short lA[128 * 32];
    __shared__ unsigned short lB[128 * 32];
    const int tid  = threadIdx.x;
    const int lane = tid & 63;
    const int wave = tid >> 6;
    const int m0 = blockIdx.y * 128;
    const int n0 = blockIdx.x * 128;
    const int wm = (wave >> 1) * 64;
    const int wn = (wave & 1) * 64;

    const int ea   = tid * 8;
    const int rowS = ea >> 5;
    const int colS = ea & 31;
    const unsigned short* gA = A  + (size_t)(m0 + rowS) * K + colS;
    const unsigned short* gB = Bm + (size_t)(n0 + rowS) * K + colS;
    const size_t stepA = (size_t)64 * K;

    const int fr = lane & 15;
    const int kg = (lane >> 4) * 8;

    f32x4 acc[4][4] = {};

    for (int kt = 0; kt < K; kt += 32) {
        gl2lds16(gA + kt,         &lA[ea]);
        gl2lds16(gA + kt + stepA, &lA[ea + 2048]);
        gl2lds16(gB + kt,         &lB[ea]);
        gl2lds16(gB + kt + stepA, &lB[ea + 2048]);
        __syncthreads();

        bf16x8 af[4], bfr[4];
#pragma unroll
        for (int mi = 0; mi < 4; ++mi)
            af[mi] = *(const bf16x8*)&lA[(wm + mi * 16 + fr) * 32 + kg];
#pragma unroll
        for (int ni = 0; ni < 4; ++ni)
            bfr[ni] = *(const bf16x8*)&lB[(wn + ni * 16 + fr) * 32 + kg];
#pragma unroll
        for (int mi = 0; mi < 4; ++mi)
#pragma unroll
            for (int ni = 0; ni < 4; ++ni)
                acc[mi][ni] = __builtin_amdgcn_mfma_f32_16x16x32_bf16(af[mi], bfr[ni], acc[mi][ni], 0, 0, 0);
        __syncthreads();
    }

    const int rb = (lane >> 4) * 4;
    const int cb = lane & 15;
#pragma unroll
    for (int mi = 0; mi < 4; ++mi) {
#pragma unroll
        for (int r = 0; r < 4; ++r) {
            const int row = m0 + wm + mi * 16 + rb + r;
            float* cp = C + (size_t)row * N + n0 + wn + cb;
#pragma unroll
            for (int ni = 0; ni < 4; ++ni)
                cp[ni * 16] = acc[mi][ni][r];
        }
    }
}

// ---------------- y GEMM: y[b, l, n] = sum_s C[b,l,s]*KV[b,s,n] + V[b,l,n]*Dp[n>>6] ----------------
// A = Cb192 (per-b 4096 x 192), B = KVt192 (per-b 768 x 192); split-precision K=192.
// Output written into dead zx columns: zx[row*1792 + 768 + n].
__global__ __launch_bounds__(256) void ygemm_kernel(
    const unsigned short* __restrict__ Cb, const unsigned short* __restrict__ KVt,
    const float* __restrict__ xc, const float* __restrict__ Dp, float* __restrict__ zx) {
    __shared__ unsigned short lA[128 * 32];
    __shared__ unsigned short lB[128 * 32];
    const int tid  = threadIdx.x;
    const int lane = tid & 63;
    const int wave = tid >> 6;
    const int b  = blockIdx.z;
    const int m0 = blockIdx.y * 128;
    const int n0 = blockIdx.x * 128;
    const int wm = (wave >> 1) * 64;
    const int wn = (wave & 1) * 64;

    const int ea   = tid * 8;
    const int rowS = ea >> 5;
    const int colS = ea & 31;
    const unsigned short* gA = Cb  + ((size_t)b * 4096 + m0 + rowS) * 192 + colS;
    const unsigned short* gB = KVt + ((size_t)b * DM   + n0 + rowS) * 192 + colS;
    const size_t stepA = (size_t)64 * 192;

    const int fr = lane & 15;
    const int kg = (lane >> 4) * 8;

    f32x4 acc[4][4] = {};

    for (int kt = 0; kt < 192; kt += 32) {
        gl2lds16(gA + kt,         &lA[ea]);
        gl2lds16(gA + kt + stepA, &lA[ea + 2048]);
        gl2lds16(gB + kt,         &lB[ea]);
        gl2lds16(gB + kt + stepA, &lB[ea + 2048]);
        __syncthreads();

        bf16x8 af[4], bfr[4];
#pragma unroll
        for (int mi = 0; mi < 4; ++mi)
            af[mi] = *(const bf16x8*)&lA[(wm + mi * 16 + fr) * 32 + kg];
#pragma unroll
        for (int ni = 0; ni < 4; ++ni)
            bfr[ni] = *(const bf16x8*)&lB[(wn + ni * 16 + fr) * 32 + kg];
#pragma unroll
        for (int mi = 0; mi < 4; ++mi)
#pragma unroll
            for (int ni = 0; ni < 4; ++ni)
                acc[mi][ni] = __builtin_amdgcn_mfma_f32_16x16x32_bf16(af[mi], bfr[ni], acc[mi][ni], 0, 0, 0);
        __syncthreads();
    }

    const int rb = (lane >> 4) * 4;
    const int cb = lane & 15;
    const float dph = Dp[(n0 + wn) >> 6];   // head is uniform across the wave's 64-wide n-span
#pragma unroll
    for (int mi = 0; mi < 4; ++mi) {
#pragma unroll
        for (int r = 0; r < 4; ++r) {
            const size_t grow = (size_t)b * 4096 + m0 + wm + mi * 16 + rb + r;
            float* yp = zx + grow * NPAD + DM + n0 + wn + cb;
            const float* vp = xc + grow * CD + n0 + wn + cb;
#pragma unroll
            for (int ni = 0; ni < 4; ++ni)
                yp[ni * 16] = acc[mi][ni][r] + vp[ni * 16] * dph;
        }
    }
}

// ---------------- dt/dA kernel ----------------
__global__ void dt_kernel(const float* __restrict__ zx, const float* __restrict__ dt_bias,
                          const float* __restrict__ A_log, float* __restrict__ dA) {
    int i = blockIdx.x * 256 + threadIdx.x;      // over BL*NH
    if (i >= BL * NH) return;
    int bl = i / NH, h = i % NH;
    float x = zx[(size_t)bl * NPAD + (DM + CD) + h] + dt_bias[h];
    float sp = (x > 20.f) ? x : log1pf(expf(x));
    dA[i] = sp * expf(A_log[h]);
}

// ---------------- depthwise conv 3x3 + bias + silu ----------------
__global__ __launch_bounds__(256) void conv_silu_kernel(
    const float* __restrict__ zx, const float* __restrict__ cwT,
    const float* __restrict__ cb, float* __restrict__ xc) {
    int idx = blockIdx.x * 256 + threadIdx.x;    // BATCH*LSEQ*(CD/4)
    if (idx >= BATCH * LSEQ * (CD / 4)) return;
    int c4  = idx % (CD / 4);
    int pix = idx / (CD / 4);
    int x = pix % WW;
    int y = (pix / WW) % HH;
    int b = pix / (WW * HH);
    int c = c4 * 4;

    float4 acc = make_float4(0.f, 0.f, 0.f, 0.f);
#pragma unroll
    for (int ky = 0; ky < 3; ++ky) {
        int yy = y + ky - 1;
        if ((unsigned)yy >= HH) continue;
#pragma unroll
        for (int kx = 0; kx < 3; ++kx) {
            int xx = x + kx - 1;
            if ((unsigned)xx >= WW) continue;
            const float4 v = *(const float4*)&zx[((size_t)b * LSEQ + yy * WW + xx) * NPAD + DM + c];
            const float4 w = *(const float4*)&cwT[(ky * 3 + kx) * CD + c];
            acc.x = fmaf(v.x, w.x, acc.x);
            acc.y = fmaf(v.y, w.y, acc.y);
            acc.z = fmaf(v.z, w.z, acc.z);
            acc.w = fmaf(v.w, w.w, acc.w);
        }
    }
    const float4 bias = *(const float4*)&cb[c];
    acc.x += bias.x; acc.y += bias.y; acc.z += bias.z; acc.w += bias.w;
    float4 o;
    o.x = acc.x / (1.f + expf(-acc.x));
    o.y = acc.y / (1.f + expf(-acc.y));
    o.z = acc.z / (1.f + expf(-acc.z));
    o.w = acc.w / (1.f + expf(-acc.w));
    *(float4*)&xc[(size_t)pix * CD + c] = o;
}

// ---------------- KV einsum: KV[b,h,s,p] = sum_l B[b,l,s] * V[b,l,h,p] * dA[b,l,h] ----------------
// 16-row staged, double-buffered LDS, one barrier per 16 rows, float4 loads.
__global__ __launch_bounds__(256) void kv_kernel(
    const float* __restrict__ xc, const float* __restrict__ dA, float* __restrict__ KV) {
    const int chunk = blockIdx.x;   // 0..KVCHUNK-1 (L split)
    const int h     = blockIdx.y;   // 0..11
    const int b     = blockIdx.z;   // 0..7
    const int l0    = chunk * (LSEQ / KVCHUNK);

    __shared__ float sB[2][16][64];
    __shared__ float sV[2][16][64];

    const int t    = threadIdx.x;
    const int row  = t >> 4;          // 0..15  (staging row)
    const int col4 = (t & 15) * 4;    // 0..60  (staging col group)
    const int s    = t & 63;          // compute: owned s
    const int pg   = t >> 6;          // compute: p-group (wave id)

    float acc[16] = {};

    // --- stage iteration 'it' into buffer 'buf' ---
    #define KV_STAGE(it, buf)                                                     \
    {                                                                             \
        const int l = l0 + (it) * 16 + row;                                       \
        const size_t base = ((size_t)b * LSEQ + l) * CD;                          \
        const float4 bv = *(const float4*)&xc[base + DM + col4];                  \
        const float4 vv = *(const float4*)&xc[base + h * HD + col4];              \
        const float sc  = dA[((size_t)b * LSEQ + l) * NH + h];                    \
        *(float4*)&sB[buf][row][col4] = bv;                                       \
        float4 vs; vs.x = vv.x * sc; vs.y = vv.y * sc;                            \
        vs.z = vv.z * sc; vs.w = vv.w * sc;                                       \
        *(float4*)&sV[buf][row][col4] = vs;                                       \
    }

    KV_STAGE(0, 0);
    __syncthreads();

    int buf = 0;
    const int NIT = (LSEQ / KVCHUNK) / 16;   // 16 iterations
    for (int it = 0; it < NIT; ++it) {
        if (it + 1 < NIT) KV_STAGE(it + 1, buf ^ 1);
#pragma unroll
        for (int q = 0; q < 16; ++q) {
            const float bb = sB[buf][q][s];
            const float4 v0 = *(const float4*)&sV[buf][q][pg * 16 + 0];
            const float4 v1 = *(const float4*)&sV[buf][q][pg * 16 + 4];
            const float4 v2 = *(const float4*)&sV[buf][q][pg * 16 + 8];
            const float4 v3 = *(const float4*)&sV[buf][q][pg * 16 + 12];
            acc[0]  = fmaf(bb, v0.x, acc[0]);  acc[1]  = fmaf(bb, v0.y, acc[1]);
            acc[2]  = fmaf(bb, v0.z, acc[2]);  acc[3]  = fmaf(bb, v0.w, acc[3]);
            acc[4]  = fmaf(bb, v1.x, acc[4]);  acc[5]  = fmaf(bb, v1.y, acc[5]);
            acc[6]  = fmaf(bb, v1.z, acc[6]);  acc[7]  = fmaf(bb, v1.w, acc[7]);
            acc[8]  = fmaf(bb, v2.x, acc[8]);  acc[9]  = fmaf(bb, v2.y, acc[9]);
            acc[10] = fmaf(bb, v2.z, acc[10]); acc[11] = fmaf(bb, v2.w, acc[11]);
            acc[12] = fmaf(bb, v3.x, acc[12]); acc[13] = fmaf(bb, v3.y, acc[13]);
            acc[14] = fmaf(bb, v3.z, acc[14]); acc[15] = fmaf(bb, v3.w, acc[15]);
        }
        __syncthreads();
        buf ^= 1;
    }
    #undef KV_STAGE

    float* kvp = KV + (((size_t)(b * NH + h) * DS + s) * HD) + pg * 16;
#pragma unroll
    for (int j = 0; j < 16; ++j) atomicAdd(&kvp[j], acc[j]);
}

// ---------------- streaming LayerNorm + *z -> bf16 (one wave per row) ----------------
__global__ __launch_bounds__(256) void ln_kernel(
    const float* __restrict__ zx, const float* __restrict__ lng, const float* __restrict__ lnb,
    unsigned short* __restrict__ yz) {
    const int row  = blockIdx.x * 4 + (threadIdx.x >> 6);
    const int lane = threadIdx.x & 63;
    const float* yb = zx + (size_t)row * NPAD + DM;
    const float* zb = zx + (size_t)row * NPAD;

    float4 yv[3];
    float s1 = 0.f;
#pragma unroll
    for (int k = 0; k < 3; ++k) {
        yv[k] = *(const float4*)&yb[lane * 4 + k * 256];
        s1 += (yv[k].x + yv[k].y) + (yv[k].z + yv[k].w);
    }
#pragma unroll
    for (int off = 32; off > 0; off >>= 1) s1 += __shfl_xor(s1, off);
    const float mu = s1 * (1.f / DM);

    float s2 = 0.f;
#pragma unroll
    for (int k = 0; k < 3; ++k) {
        float dx = yv[k].x - mu, dy = yv[k].y - mu, dz = yv[k].z - mu, dw = yv[k].w - mu;
        s2 += (dx * dx + dy * dy) + (dz * dz + dw * dw);
    }
#pragma unroll
    for (int off = 32; off > 0; off >>= 1) s2 += __shfl_xor(s2, off);
    const float rs = rsqrtf(s2 * (1.f / DM) + 1e-5f);

#pragma unroll
    for (int k = 0; k < 3; ++k) {
        const int j = lane * 4 + k * 256;
        const float4 g  = *(const float4*)&lng[j];
        const float4 bb = *(const float4*)&lnb[j];
        const float4 zv = *(const float4*)&zb[j];
        ushort4 o;
        o.x = f2bf(((yv[k].x - mu) * rs * g.x + bb.x) * zv.x);
        o.y = f2bf(((yv[k].y - mu) * rs * g.y + bb.y) * zv.y);
        o.z = f2bf(((yv[k].z - mu) * rs * g.z + bb.z) * zv.z);
        o.w = f2bf(((yv[k].w - mu) * rs * g.w + bb.w) * zv.w);
        *(ushort4*)&yz[(size_t)row * DM + j] = o;
    }
}

// ---------------- launch ----------------
extern "C" void kernel_launch(void* const* d_in, const int* in_sizes, int n_in,
                              void* d_out, int out_size, void* d_ws, size_t ws_size,
                              hipStream_t stream) {
    const float* u       = (const float*)d_in[0];
    const float* w_in    = (const float*)d_in[1];
    const float* conv_w  = (const float*)d_in[2];
    const float* conv_b  = (const float*)d_in[3];
    const float* dt_bias = (const float*)d_in[4];
    const float* A_log   = (const float*)d_in[5];
    const float* Dp      = (const float*)d_in[6];
    const float* ln_g    = (const float*)d_in[7];
    const float* ln_b    = (const float*)d_in[8];
    const float* w_out   = (const float*)d_in[9];

    char* ws = (char*)d_ws;
    float*          zx   = (float*)(ws + OFF_ZX);
    float*          xc   = (float*)(ws + OFF_XC);
    float*          dAb  = (float*)(ws + OFF_DA);
    unsigned short* ubf  = (unsigned short*)(ws + OFF_UBF);
    unsigned short* yzbf = ubf;                              // reuse after GEMM1 consumed ubf
    unsigned short* Cb   = (unsigned short*)(ws + OFF_CB);   // overlays ubf (dead after GEMM1)
    unsigned short* KVt  = (unsigned short*)(ws + OFF_KVT);
    unsigned short* wibf = (unsigned short*)(ws + OFF_WI);
    unsigned short* wobf = (unsigned short*)(ws + OFF_WO);
    float*          cwT  = (float*)(ws + OFF_CWT);

    float* outp = (float*)d_out;
    float* KV   = outp + OUT_ELEMS;

    hipMemsetAsync(KV, 0, (size_t)KV_ELEMS * sizeof(float), stream);

    cvt_u_kernel<<<(BL * DM / 8 + 255) / 256, 256, 0, stream>>>(u, ubf, BL * DM / 8);
    cvt_win_kernel<<<(NPAD * DM / 8 + 255) / 256, 256, 0, stream>>>(w_in, wibf);
    cvt_u_kernel<<<(DM * DM / 8 + 255) / 256, 256, 0, stream>>>(w_out, wobf, DM * DM / 8);
    cvt_cw_kernel<<<(9 * CD + 255) / 256, 256, 0, stream>>>(conv_w, cwT);

    gemm_bt_bf16<<<dim3(NPAD / 128, BL / 128), 256, 0, stream>>>(ubf, wibf, zx, BL, NPAD, DM);

    dt_kernel<<<(BL * NH + 255) / 256, 256, 0, stream>>>(zx, dt_bias, A_log, dAb);
    conv_silu_kernel<<<(BATCH * LSEQ * (CD / 4) + 255) / 256, 256, 0, stream>>>(zx, cwT, conv_b, xc);

    kv_kernel<<<dim3(KVCHUNK, NH, BATCH), 256, 0, stream>>>(xc, dAb, KV);

    cvt_c_kernel<<<(BL * 16 + 255) / 256, 256, 0, stream>>>(xc, Cb);
    cvt_kv_kernel<<<(BATCH * DM * DS + 255) / 256, 256, 0, stream>>>(KV, KVt);
    ygemm_kernel<<<dim3(DM / 128, 4096 / 128, BATCH), 256, 0, stream>>>(Cb, KVt, xc, Dp, zx);

    ln_kernel<<<BL / 4, 256, 0, stream>>>(zx, ln_g, ln_b, yzbf);

    gemm_bt_bf16<<<dim3(DM / 128, BL / 128), 256, 0, stream>>>(yzbf, wobf, outp, BL, DM, DM);
}

// Round 11
// 671.599 us; speedup vs baseline: 1.3975x; 1.3975x over previous
//
#include <hip/hip_runtime.h>

// ---------------- constants ----------------
#define BATCH 8
#define HH 64
#define WW 64
#define LSEQ 4096                    // HH*WW
#define BL 32768                     // BATCH*LSEQ
#define DM 768
#define CD 896                       // CONV_DIM
#define NPROJ 1676                   // D_IN_PROJ
#define NPAD 1792                    // padded to 14*128
#define NH 12
#define HD 64
#define DS 64
#define OUT_ELEMS 25165824           // BL*DM
#define KV_ELEMS 393216              // BATCH*NH*DS*HD
#define KVCHUNK 8                    // K-split for kv einsum

// workspace layout (bytes)
#define OFF_ZX   ((size_t)0)
#define SZ_ZX    ((size_t)BL * NPAD * 4)
#define OFF_XC   (OFF_ZX + SZ_ZX)
#define SZ_XC    ((size_t)BL * CD * 4)
#define OFF_DA   (OFF_XC + SZ_XC)
#define SZ_DA    ((size_t)BL * NH * 4)
#define OFF_UBF  (OFF_DA + SZ_DA)            // u bf16; later overlaid: Cb192 / KVt192 / KV partials / yz bf16
#define SZ_UBF   ((size_t)BL * DM * 2)
#define OFF_WI   (OFF_UBF + SZ_UBF)
#define SZ_WI    ((size_t)NPAD * DM * 2)
#define OFF_WO   (OFF_WI + SZ_WI)
#define SZ_WO    ((size_t)DM * DM * 2)
#define OFF_CWT  (OFF_WO + SZ_WO)            // 9*896 floats

// overlays inside the UBF region (ubf dead after gemm1; yz written only after ygemm)
#define OFF_CB   OFF_UBF                          // [0, 12.6 MB)   Cmat split-precision
#define OFF_KVT  (OFF_UBF + (size_t)20*1024*1024) // [20, 22.4 MB)  KVt bf16
#define OFF_KVP  (OFF_UBF + (size_t)24*1024*1024) // [24, 36.6 MB)  KV fp32 partials (8 x 1.5 MB)

typedef __attribute__((ext_vector_type(4))) float f32x4;
typedef __attribute__((ext_vector_type(8))) short bf16x8;

__device__ __forceinline__ unsigned short f2bf(float f) {
    unsigned int u = __float_as_uint(f);
    u += 0x7FFFu + ((u >> 16) & 1u);   // round to nearest even
    return (unsigned short)(u >> 16);
}
__device__ __forceinline__ float bf2f(unsigned short h) {
    return __uint_as_float(((unsigned int)h) << 16);
}

__device__ __forceinline__ void gl2lds16(const void* g, void* l) {
    __builtin_amdgcn_global_load_lds(
        (const __attribute__((address_space(1))) unsigned int*)g,
        (__attribute__((address_space(3))) unsigned int*)l, 16, 0, 0);
}

// ---------------- conversion kernels ----------------
__global__ void cvt_u_kernel(const float* __restrict__ in, unsigned short* __restrict__ out, int n8) {
    int i = blockIdx.x * 256 + threadIdx.x;
    if (i >= n8) return;
    const float4* p = (const float4*)in + (size_t)i * 2;
    float4 a = p[0], b = p[1];
    union { unsigned short s[8]; uint4 v; } r;
    r.s[0] = f2bf(a.x); r.s[1] = f2bf(a.y); r.s[2] = f2bf(a.z); r.s[3] = f2bf(a.w);
    r.s[4] = f2bf(b.x); r.s[5] = f2bf(b.y); r.s[6] = f2bf(b.z); r.s[7] = f2bf(b.w);
    ((uint4*)out)[i] = r.v;
}

// w_in (1676,768) -> bf16 (1792,768) zero padded rows
__global__ void cvt_win_kernel(const float* __restrict__ in, unsigned short* __restrict__ out) {
    int i = blockIdx.x * 256 + threadIdx.x;        // i indexes groups of 8
    if (i >= NPAD * DM / 8) return;
    int row = (i * 8) / DM;
    union { unsigned short s[8]; uint4 v; } r;
    if (row < NPROJ) {
        const float4* p = (const float4*)in + (size_t)i * 2;
        float4 a = p[0], b = p[1];
        r.s[0] = f2bf(a.x); r.s[1] = f2bf(a.y); r.s[2] = f2bf(a.z); r.s[3] = f2bf(a.w);
        r.s[4] = f2bf(b.x); r.s[5] = f2bf(b.y); r.s[6] = f2bf(b.z); r.s[7] = f2bf(b.w);
    } else {
        r.v = make_uint4(0, 0, 0, 0);
    }
    ((uint4*)out)[i] = r.v;
}

// conv_w (896,1,3,3) -> cwT (9, 896)
__global__ void cvt_cw_kernel(const float* __restrict__ in, float* __restrict__ out) {
    int i = blockIdx.x * 256 + threadIdx.x;
    if (i >= 9 * CD) return;
    int tap = i / CD, c = i % CD;
    out[i] = in[c * 9 + tap];
}

// Cmat (xc[...,832:896]) -> split-precision K=192 layout [hi | lo | hi]
__global__ void cvt_c_kernel(const float* __restrict__ xc, unsigned short* __restrict__ Cb) {
    int i = blockIdx.x * 256 + threadIdx.x;     // BL*16 float4-groups
    if (i >= BL * 16) return;
    int row = i >> 4, c = (i & 15) * 4;
    float4 v = *(const float4*)&xc[(size_t)row * CD + (DM + DS) + c];
    ushort4 hi, lo;
    hi.x = f2bf(v.x); lo.x = f2bf(v.x - bf2f(hi.x));
    hi.y = f2bf(v.y); lo.y = f2bf(v.y - bf2f(hi.y));
    hi.z = f2bf(v.z); lo.z = f2bf(v.z - bf2f(hi.z));
    hi.w = f2bf(v.w); lo.w = f2bf(v.w - bf2f(hi.w));
    unsigned short* base = Cb + (size_t)row * 192;
    *(ushort4*)&base[c]       = hi;
    *(ushort4*)&base[64 + c]  = lo;
    *(ushort4*)&base[128 + c] = hi;
}

// sum KV partials -> final fp32 KV (d_out). p-fastest => fully coalesced.
__global__ void kv_reduce_kernel(const float* __restrict__ KVP, float* __restrict__ KV) {
    int i = blockIdx.x * 256 + threadIdx.x;     // over KV_ELEMS
    if (i >= KV_ELEMS) return;
    float sum = 0.f;
#pragma unroll
    for (int c = 0; c < KVCHUNK; ++c)
        sum += KVP[(size_t)c * KV_ELEMS + i];
    KV[i] = sum;
}

// KV (b,h,s,p) fp32 -> KVt (b, n=h*64+p, k=192) bf16 [H | H | L]
__global__ void cvt_kv_kernel(const float* __restrict__ KV, unsigned short* __restrict__ KVt) {
    int i = blockIdx.x * 256 + threadIdx.x;     // 8*768*64
    if (i >= BATCH * DM * DS) return;
    int s = i & 63;
    int n = (i >> 6) % DM;
    int b = i / (DM * DS);
    int h = n >> 6, p = n & 63;
    float x = KV[(((size_t)(b * NH + h) * DS + s) * HD) + p];
    unsigned short H = f2bf(x);
    unsigned short L = f2bf(x - bf2f(H));
    unsigned short* base = KVt + ((size_t)(b * DM + n)) * 192;
    base[s] = H; base[64 + s] = H; base[128 + s] = L;
}

// ---------------- bf16 GEMM (m97 structure): C(M,N) = A(M,K) * B(N,K)^T ----------------
// XCD-aware bijective block swizzle (requires gridDim.x*gridDim.y % 8 == 0;
// holds for both call sites: 14*256=3584, 6*256=1536). Any bijection is
// functionally identical -- perf-only change.
__global__ __launch_bounds__(256) void gemm_bt_bf16(
    const unsigned short* __restrict__ A,
    const unsigned short* __restrict__ Bm,
    float* __restrict__ C, int M, int N, int K) {
    __shared__ unsigned short lA[128 * 32];
    __shared__ unsigned short lB[128 * 32];
    const int tid  = threadIdx.x;
    const int lane = tid & 63;
    const int wave = tid >> 6;

    const int nwg  = gridDim.x * gridDim.y;
    int flat = blockIdx.y * gridDim.x + blockIdx.x;
    flat = (flat & 7) * (nwg >> 3) + (flat >> 3);   // XCD k -> contiguous tile band
    const int m0 = (flat / gridDim.x) * 128;
    const int n0 = (flat % gridDim.x) * 128;

    const int wm = (wave >> 1) * 64;
    const int wn = (wave & 1) * 64;

    const int ea   = tid * 8;
    const int rowS = ea >> 5;
    const int colS = ea & 31;
    const unsigned short* gA = A  + (size_t)(m0 + rowS) * K + colS;
    const unsigned short* gB = Bm + (size_t)(n0 + rowS) * K + colS;
    const size_t stepA = (size_t)64 * K;

    const int fr = lane & 15;
    const int kg = (lane >> 4) * 8;

    f32x4 acc[4][4] = {};

    for (int kt = 0; kt < K; kt += 32) {
        gl2lds16(gA + kt,         &lA[ea]);
        gl2lds16(gA + kt + stepA, &lA[ea + 2048]);
        gl2lds16(gB + kt,         &lB[ea]);
        gl2lds16(gB + kt + stepA, &lB[ea + 2048]);
        __syncthreads();

        bf16x8 af[4], bfr[4];
#pragma unroll
        for (int mi = 0; mi < 4; ++mi)
            af[mi] = *(const bf16x8*)&lA[(wm + mi * 16 + fr) * 32 + kg];
#pragma unroll
        for (int ni = 0; ni < 4; ++ni)
            bfr[ni] = *(const bf16x8*)&lB[(wn + ni * 16 + fr) * 32 + kg];
#pragma unroll
        for (int mi = 0; mi < 4; ++mi)
#pragma unroll
            for (int ni = 0; ni < 4; ++ni)
                acc[mi][ni] = __builtin_amdgcn_mfma_f32_16x16x32_bf16(af[mi], bfr[ni], acc[mi][ni], 0, 0, 0);
        __syncthreads();
    }

    const int rb = (lane >> 4) * 4;
    const int cb = lane & 15;
#pragma unroll
    for (int mi = 0; mi < 4; ++mi) {
#pragma unroll
        for (int r = 0; r < 4; ++r) {
            const int row = m0 + wm + mi * 16 + rb + r;
            float* cp = C + (size_t)row * N + n0 + wn + cb;
#pragma unroll
            for (int ni = 0; ni < 4; ++ni)
                cp[ni * 16] = acc[mi][ni][r];
        }
    }
}

// ---------------- y GEMM: y[b, l, n] = sum_s C[b,l,s]*KV[b,s,n] + V[b,l,n]*Dp[n>>6] ----------------
// A = Cb192 (per-b 4096 x 192), B = KVt192 (per-b 768 x 192); split-precision K=192.
// Output written into dead zx columns: zx[row*1792 + 768 + n].
__global__ __launch_bounds__(256) void ygemm_kernel(
    const unsigned short* __restrict__ Cb, const unsigned short* __restrict__ KVt,
    const float* __restrict__ xc, const float* __restrict__ Dp, float* __restrict__ zx) {
    __shared__ unsigned short lA[128 * 32];
    __shared__ unsigned short lB[128 * 32];
    const int tid  = threadIdx.x;
    const int lane = tid & 63;
    const int wave = tid >> 6;
    const int b  = blockIdx.z;
    const int m0 = blockIdx.y * 128;
    const int n0 = blockIdx.x * 128;
    const int wm = (wave >> 1) * 64;
    const int wn = (wave & 1) * 64;

    const int ea   = tid * 8;
    const int rowS = ea >> 5;
    const int colS = ea & 31;
    const unsigned short* gA = Cb  + ((size_t)b * 4096 + m0 + rowS) * 192 + colS;
    const unsigned short* gB = KVt + ((size_t)b * DM   + n0 + rowS) * 192 + colS;
    const size_t stepA = (size_t)64 * 192;

    const int fr = lane & 15;
    const int kg = (lane >> 4) * 8;

    f32x4 acc[4][4] = {};

    for (int kt = 0; kt < 192; kt += 32) {
        gl2lds16(gA + kt,         &lA[ea]);
        gl2lds16(gA + kt + stepA, &lA[ea + 2048]);
        gl2lds16(gB + kt,         &lB[ea]);
        gl2lds16(gB + kt + stepA, &lB[ea + 2048]);
        __syncthreads();

        bf16x8 af[4], bfr[4];
#pragma unroll
        for (int mi = 0; mi < 4; ++mi)
            af[mi] = *(const bf16x8*)&lA[(wm + mi * 16 + fr) * 32 + kg];
#pragma unroll
        for (int ni = 0; ni < 4; ++ni)
            bfr[ni] = *(const bf16x8*)&lB[(wn + ni * 16 + fr) * 32 + kg];
#pragma unroll
        for (int mi = 0; mi < 4; ++mi)
#pragma unroll
            for (int ni = 0; ni < 4; ++ni)
                acc[mi][ni] = __builtin_amdgcn_mfma_f32_16x16x32_bf16(af[mi], bfr[ni], acc[mi][ni], 0, 0, 0);
        __syncthreads();
    }

    const int rb = (lane >> 4) * 4;
    const int cb = lane & 15;
    const float dph = Dp[(n0 + wn) >> 6];   // head is uniform across the wave's 64-wide n-span
#pragma unroll
    for (int mi = 0; mi < 4; ++mi) {
#pragma unroll
        for (int r = 0; r < 4; ++r) {
            const size_t grow = (size_t)b * 4096 + m0 + wm + mi * 16 + rb + r;
            float* yp = zx + grow * NPAD + DM + n0 + wn + cb;
            const float* vp = xc + grow * CD + n0 + wn + cb;
#pragma unroll
            for (int ni = 0; ni < 4; ++ni)
                yp[ni * 16] = acc[mi][ni][r] + vp[ni * 16] * dph;
        }
    }
}

// ---------------- dt/dA kernel ----------------
__global__ void dt_kernel(const float* __restrict__ zx, const float* __restrict__ dt_bias,
                          const float* __restrict__ A_log, float* __restrict__ dA) {
    int i = blockIdx.x * 256 + threadIdx.x;      // over BL*NH
    if (i >= BL * NH) return;
    int bl = i / NH, h = i % NH;
    float x = zx[(size_t)bl * NPAD + (DM + CD) + h] + dt_bias[h];
    float sp = (x > 20.f) ? x : log1pf(expf(x));
    dA[i] = sp * expf(A_log[h]);
}

// ---------------- depthwise conv 3x3 + bias + silu ----------------
__global__ __launch_bounds__(256) void conv_silu_kernel(
    const float* __restrict__ zx, const float* __restrict__ cwT,
    const float* __restrict__ cb, float* __restrict__ xc) {
    int idx = blockIdx.x * 256 + threadIdx.x;    // BATCH*LSEQ*(CD/4)
    if (idx >= BATCH * LSEQ * (CD / 4)) return;
    int c4  = idx % (CD / 4);
    int pix = idx / (CD / 4);
    int x = pix % WW;
    int y = (pix / WW) % HH;
    int b = pix / (WW * HH);
    int c = c4 * 4;

    float4 acc = make_float4(0.f, 0.f, 0.f, 0.f);
#pragma unroll
    for (int ky = 0; ky < 3; ++ky) {
        int yy = y + ky - 1;
        if ((unsigned)yy >= HH) continue;
#pragma unroll
        for (int kx = 0; kx < 3; ++kx) {
            int xx = x + kx - 1;
            if ((unsigned)xx >= WW) continue;
            const float4 v = *(const float4*)&zx[((size_t)b * LSEQ + yy * WW + xx) * NPAD + DM + c];
            const float4 w = *(const float4*)&cwT[(ky * 3 + kx) * CD + c];
            acc.x = fmaf(v.x, w.x, acc.x);
            acc.y = fmaf(v.y, w.y, acc.y);
            acc.z = fmaf(v.z, w.z, acc.z);
            acc.w = fmaf(v.w, w.w, acc.w);
        }
    }
    const float4 bias = *(const float4*)&cb[c];
    acc.x += bias.x; acc.y += bias.y; acc.z += bias.z; acc.w += bias.w;
    float4 o;
    o.x = acc.x / (1.f + expf(-acc.x));
    o.y = acc.y / (1.f + expf(-acc.y));
    o.z = acc.z / (1.f + expf(-acc.z));
    o.w = acc.w / (1.f + expf(-acc.w));
    *(float4*)&xc[(size_t)pix * CD + c] = o;
}

// ---------------- KV einsum: KVP[chunk][b,h,s,p] = sum_l B[b,l,s] * V[b,l,h,p] * dA[b,l,h] ----------------
// 16-row staged, double-buffered LDS, one barrier per 16 rows, float4 loads, plain stores (no atomics).
__global__ __launch_bounds__(256) void kv_kernel(
    const float* __restrict__ xc, const float* __restrict__ dA, float* __restrict__ KVP) {
    const int chunk = blockIdx.x;   // 0..KVCHUNK-1 (L split)
    const int h     = blockIdx.y;   // 0..11
    const int b     = blockIdx.z;   // 0..7
    const int l0    = chunk * (LSEQ / KVCHUNK);

    __shared__ float sB[2][16][64];
    __shared__ float sV[2][16][64];

    const int t    = threadIdx.x;
    const int row  = t >> 4;          // 0..15  (staging row)
    const int col4 = (t & 15) * 4;    // 0..60  (staging col group)
    const int s    = t & 63;          // compute: owned s
    const int pg   = t >> 6;          // compute: p-group (wave id)

    float acc[16] = {};

    // --- stage iteration 'it' into buffer 'buf' ---
    #define KV_STAGE(it, buf)                                                     \
    {                                                                             \
        const int l = l0 + (it) * 16 + row;                                       \
        const size_t base = ((size_t)b * LSEQ + l) * CD;                          \
        const float4 bv = *(const float4*)&xc[base + DM + col4];                  \
        const float4 vv = *(const float4*)&xc[base + h * HD + col4];              \
        const float sc  = dA[((size_t)b * LSEQ + l) * NH + h];                    \
        *(float4*)&sB[buf][row][col4] = bv;                                       \
        float4 vs; vs.x = vv.x * sc; vs.y = vv.y * sc;                            \
        vs.z = vv.z * sc; vs.w = vv.w * sc;                                       \
        *(float4*)&sV[buf][row][col4] = vs;                                       \
    }

    KV_STAGE(0, 0);
    __syncthreads();

    int buf = 0;
    const int NIT = (LSEQ / KVCHUNK) / 16;   // 32 iterations
    for (int it = 0; it < NIT; ++it) {
        if (it + 1 < NIT) KV_STAGE(it + 1, buf ^ 1);
#pragma unroll
        for (int q = 0; q < 16; ++q) {
            const float bb = sB[buf][q][s];
            const float4 v0 = *(const float4*)&sV[buf][q][pg * 16 + 0];
            const float4 v1 = *(const float4*)&sV[buf][q][pg * 16 + 4];
            const float4 v2 = *(const float4*)&sV[buf][q][pg * 16 + 8];
            const float4 v3 = *(const float4*)&sV[buf][q][pg * 16 + 12];
            acc[0]  = fmaf(bb, v0.x, acc[0]);  acc[1]  = fmaf(bb, v0.y, acc[1]);
            acc[2]  = fmaf(bb, v0.z, acc[2]);  acc[3]  = fmaf(bb, v0.w, acc[3]);
            acc[4]  = fmaf(bb, v1.x, acc[4]);  acc[5]  = fmaf(bb, v1.y, acc[5]);
            acc[6]  = fmaf(bb, v1.z, acc[6]);  acc[7]  = fmaf(bb, v1.w, acc[7]);
            acc[8]  = fmaf(bb, v2.x, acc[8]);  acc[9]  = fmaf(bb, v2.y, acc[9]);
            acc[10] = fmaf(bb, v2.z, acc[10]); acc[11] = fmaf(bb, v2.w, acc[11]);
            acc[12] = fmaf(bb, v3.x, acc[12]); acc[13] = fmaf(bb, v3.y, acc[13]);
            acc[14] = fmaf(bb, v3.z, acc[14]); acc[15] = fmaf(bb, v3.w, acc[15]);
        }
        __syncthreads();
        buf ^= 1;
    }
    #undef KV_STAGE

    float* kvp = KVP + ((size_t)chunk * KV_ELEMS)
               + (((size_t)(b * NH + h) * DS + s) * HD) + pg * 16;
    *(float4*)&kvp[0]  = make_float4(acc[0],  acc[1],  acc[2],  acc[3]);
    *(float4*)&kvp[4]  = make_float4(acc[4],  acc[5],  acc[6],  acc[7]);
    *(float4*)&kvp[8]  = make_float4(acc[8],  acc[9],  acc[10], acc[11]);
    *(float4*)&kvp[12] = make_float4(acc[12], acc[13], acc[14], acc[15]);
}

// ---------------- streaming LayerNorm + *z -> bf16 (one wave per row) ----------------
__global__ __launch_bounds__(256) void ln_kernel(
    const float* __restrict__ zx, const float* __restrict__ lng, const float* __restrict__ lnb,
    unsigned short* __restrict__ yz) {
    const int row  = blockIdx.x * 4 + (threadIdx.x >> 6);
    const int lane = threadIdx.x & 63;
    const float* yb = zx + (size_t)row * NPAD + DM;
    const float* zb = zx + (size_t)row * NPAD;

    float4 yv[3];
    float s1 = 0.f;
#pragma unroll
    for (int k = 0; k < 3; ++k) {
        yv[k] = *(const float4*)&yb[lane * 4 + k * 256];
        s1 += (yv[k].x + yv[k].y) + (yv[k].z + yv[k].w);
    }
#pragma unroll
    for (int off = 32; off > 0; off >>= 1) s1 += __shfl_xor(s1, off);
    const float mu = s1 * (1.f / DM);

    float s2 = 0.f;
#pragma unroll
    for (int k = 0; k < 3; ++k) {
        float dx = yv[k].x - mu, dy = yv[k].y - mu, dz = yv[k].z - mu, dw = yv[k].w - mu;
        s2 += (dx * dx + dy * dy) + (dz * dz + dw * dw);
    }
#pragma unroll
    for (int off = 32; off > 0; off >>= 1) s2 += __shfl_xor(s2, off);
    const float rs = rsqrtf(s2 * (1.f / DM) + 1e-5f);

#pragma unroll
    for (int k = 0; k < 3; ++k) {
        const int j = lane * 4 + k * 256;
        const float4 g  = *(const float4*)&lng[j];
        const float4 bb = *(const float4*)&lnb[j];
        const float4 zv = *(const float4*)&zb[j];
        ushort4 o;
        o.x = f2bf(((yv[k].x - mu) * rs * g.x + bb.x) * zv.x);
        o.y = f2bf(((yv[k].y - mu) * rs * g.y + bb.y) * zv.y);
        o.z = f2bf(((yv[k].z - mu) * rs * g.z + bb.z) * zv.z);
        o.w = f2bf(((yv[k].w - mu) * rs * g.w + bb.w) * zv.w);
        *(ushort4*)&yz[(size_t)row * DM + j] = o;
    }
}

// ---------------- launch ----------------
extern "C" void kernel_launch(void* const* d_in, const int* in_sizes, int n_in,
                              void* d_out, int out_size, void* d_ws, size_t ws_size,
                              hipStream_t stream) {
    const float* u       = (const float*)d_in[0];
    const float* w_in    = (const float*)d_in[1];
    const float* conv_w  = (const float*)d_in[2];
    const float* conv_b  = (const float*)d_in[3];
    const float* dt_bias = (const float*)d_in[4];
    const float* A_log   = (const float*)d_in[5];
    const float* Dp      = (const float*)d_in[6];
    const float* ln_g    = (const float*)d_in[7];
    const float* ln_b    = (const float*)d_in[8];
    const float* w_out   = (const float*)d_in[9];

    char* ws = (char*)d_ws;
    float*          zx   = (float*)(ws + OFF_ZX);
    float*          xc   = (float*)(ws + OFF_XC);
    float*          dAb  = (float*)(ws + OFF_DA);
    unsigned short* ubf  = (unsigned short*)(ws + OFF_UBF);
    unsigned short* yzbf = ubf;                              // reuse after GEMM1 consumed ubf
    unsigned short* Cb   = (unsigned short*)(ws + OFF_CB);   // overlays ubf (dead after GEMM1)
    unsigned short* KVt  = (unsigned short*)(ws + OFF_KVT);
    float*          KVP  = (float*)(ws + OFF_KVP);
    unsigned short* wibf = (unsigned short*)(ws + OFF_WI);
    unsigned short* wobf = (unsigned short*)(ws + OFF_WO);
    float*          cwT  = (float*)(ws + OFF_CWT);

    float* outp = (float*)d_out;
    float* KV   = outp + OUT_ELEMS;

    cvt_u_kernel<<<(BL * DM / 8 + 255) / 256, 256, 0, stream>>>(u, ubf, BL * DM / 8);
    cvt_win_kernel<<<(NPAD * DM / 8 + 255) / 256, 256, 0, stream>>>(w_in, wibf);
    cvt_u_kernel<<<(DM * DM / 8 + 255) / 256, 256, 0, stream>>>(w_out, wobf, DM * DM / 8);
    cvt_cw_kernel<<<(9 * CD + 255) / 256, 256, 0, stream>>>(conv_w, cwT);

    gemm_bt_bf16<<<dim3(NPAD / 128, BL / 128), 256, 0, stream>>>(ubf, wibf, zx, BL, NPAD, DM);

    dt_kernel<<<(BL * NH + 255) / 256, 256, 0, stream>>>(zx, dt_bias, A_log, dAb);
    conv_silu_kernel<<<(BATCH * LSEQ * (CD / 4) + 255) / 256, 256, 0, stream>>>(zx, cwT, conv_b, xc);

    kv_kernel<<<dim3(KVCHUNK, NH, BATCH), 256, 0, stream>>>(xc, dAb, KVP);
    kv_reduce_kernel<<<(KV_ELEMS + 255) / 256, 256, 0, stream>>>(KVP, KV);

    cvt_c_kernel<<<(BL * 16 + 255) / 256, 256, 0, stream>>>(xc, Cb);
    cvt_kv_kernel<<<(BATCH * DM * DS + 255) / 256, 256, 0, stream>>>(KV, KVt);
    ygemm_kernel<<<dim3(DM / 128, 4096 / 128, BATCH), 256, 0, stream>>>(Cb, KVt, xc, Dp, zx);

    ln_kernel<<<BL / 4, 256, 0, stream>>>(zx, ln_g, ln_b, yzbf);

    gemm_bt_bf16<<<dim3(DM / 128, BL / 128), 256, 0, stream>>>(yzbf, wobf, outp, BL, DM, DM);
}